// Round 1
// baseline (1076.109 us; speedup 1.0000x reference)
//
#include <hip/hip_runtime.h>

#define BB 256
#define TT 2048
#define HH 32
#define G4 128   // 4*H
#define POS 32   // (b,t) positions per xproj block

// Fast sigmoid/tanh: v_exp_f32 (+mul) and v_rcp_f32, both ~1 ulp.
__device__ __forceinline__ float fsig(float x) {
    return __builtin_amdgcn_rcpf(1.0f + __expf(-x));
}
__device__ __forceinline__ float ftanh(float x) {
    // 1 - 2/(exp(2x)+1); exp(inf)->inf -> 1, exp(-inf)->0 -> -1 (correct saturation)
    return 1.0f - 2.0f * __builtin_amdgcn_rcpf(__expf(2.0f * x) + 1.0f);
}

// ---------------------------------------------------------------------------
// Kernel 1: x_gates[bt][j][g] = W_ih[g*32+j,:] . x[bt,:] + b_ih + b_hh
// Layout [bt][j][g] so the recurrent kernel loads one float4 per (lane, step).
// Thread tid in [0,128): g = tid&3, j = tid>>2  (tid == j*4+g, coalesced store).
// ---------------------------------------------------------------------------
__global__ __launch_bounds__(128) void xproj_kernel(
    const float* __restrict__ x, const float* __restrict__ W_ih,
    const float* __restrict__ b_ih, const float* __restrict__ b_hh,
    float* __restrict__ xg) {
  const int tid = threadIdx.x;
  const int g = tid & 3, j = tid >> 2;
  const int row = g * HH + j;

  // W_ih row in registers
  float w[HH];
  const float4* wr = (const float4*)(W_ih + (size_t)row * HH);
#pragma unroll
  for (int k4 = 0; k4 < HH / 4; ++k4) {
    float4 v = wr[k4];
    w[k4 * 4 + 0] = v.x; w[k4 * 4 + 1] = v.y;
    w[k4 * 4 + 2] = v.z; w[k4 * 4 + 3] = v.w;
  }
  const float bias = b_ih[row] + b_hh[row];

  __shared__ float4 sx[POS * HH / 4];  // 256 float4 = 4 KB
  const size_t bt0 = (size_t)blockIdx.x * POS;
  const float4* xsrc = (const float4*)x + bt0 * (HH / 4);
  sx[tid] = xsrc[tid];
  sx[tid + 128] = xsrc[tid + 128];
  __syncthreads();

#pragma unroll 4
  for (int p = 0; p < POS; ++p) {
    const float4* xr = sx + p * (HH / 4);
    float a = bias;
#pragma unroll
    for (int k4 = 0; k4 < HH / 4; ++k4) {
      float4 v = xr[k4];  // broadcast LDS read (all lanes same addr)
      a = fmaf(w[k4 * 4 + 0], v.x, a);
      a = fmaf(w[k4 * 4 + 1], v.y, a);
      a = fmaf(w[k4 * 4 + 2], v.z, a);
      a = fmaf(w[k4 * 4 + 3], v.w, a);
    }
    xg[(bt0 + p) * G4 + tid] = a;
  }
}

// ---------------------------------------------------------------------------
// Kernel 2: the recurrence. One batch row per wave; 256 blocks x 64 threads.
// Gate-split: lanes 0-31 own gates (i,f) for hidden j=lane, lanes 32-63 own
// (g,o). Each half computes FULL K=32 dot products for its two gates with
// W_hh rows in VGPRs and h broadcast from lanes 0-31 via v_readlane (SGPRs).
// Complete pre-activations are exchanged across halves with shfl_xor(32);
// both halves then compute identical (c,h) — no divergence, no LDS.
// ---------------------------------------------------------------------------
template <bool HAS_XG>
__global__ __launch_bounds__(64, 1) void lstm_rec(
    const float* __restrict__ x, const float* __restrict__ W_ih,
    const float* __restrict__ W_hh, const float* __restrict__ b_ih,
    const float* __restrict__ b_hh, const float4* __restrict__ xg,
    float* __restrict__ out) {
  const int b = blockIdx.x;
  const int lane = threadIdx.x;
  const int j = lane & 31;
  const int hf = lane >> 5;           // 0: gates i,f   1: gates g,o
  const int r0 = (hf * 2 + 0) * HH + j;
  const int r1 = (hf * 2 + 1) * HH + j;

  float whh0[HH], whh1[HH];
  {
    const float4* w0 = (const float4*)(W_hh + (size_t)r0 * HH);
    const float4* w1 = (const float4*)(W_hh + (size_t)r1 * HH);
#pragma unroll
    for (int k4 = 0; k4 < HH / 4; ++k4) {
      float4 a = w0[k4], c = w1[k4];
      whh0[k4 * 4 + 0] = a.x; whh0[k4 * 4 + 1] = a.y;
      whh0[k4 * 4 + 2] = a.z; whh0[k4 * 4 + 3] = a.w;
      whh1[k4 * 4 + 0] = c.x; whh1[k4 * 4 + 1] = c.y;
      whh1[k4 * 4 + 2] = c.z; whh1[k4 * 4 + 3] = c.w;
    }
  }

  float wih0[HH], wih1[HH];
  float bias0 = 0.f, bias1 = 0.f;
  if (!HAS_XG) {
    const float4* w0 = (const float4*)(W_ih + (size_t)r0 * HH);
    const float4* w1 = (const float4*)(W_ih + (size_t)r1 * HH);
#pragma unroll
    for (int k4 = 0; k4 < HH / 4; ++k4) {
      float4 a = w0[k4], c = w1[k4];
      wih0[k4 * 4 + 0] = a.x; wih0[k4 * 4 + 1] = a.y;
      wih0[k4 * 4 + 2] = a.z; wih0[k4 * 4 + 3] = a.w;
      wih1[k4 * 4 + 0] = c.x; wih1[k4 * 4 + 1] = c.y;
      wih1[k4 * 4 + 2] = c.z; wih1[k4 * 4 + 3] = c.w;
    }
    bias0 = b_ih[r0] + b_hh[r0];
    bias1 = b_ih[r1] + b_hh[r1];
  }

  float h = 0.f, c = 0.f;
  const size_t base = (size_t)b * TT;

  float4 xg_n = make_float4(0.f, 0.f, 0.f, 0.f);
  float xv_n = 0.f;
  if (HAS_XG) xg_n = xg[base * (G4 / 4) + j];
  else        xv_n = x[base * HH + j];

  for (int t = 0; t < TT; ++t) {
    float4 xgc = xg_n;
    float xvc = xv_n;
    {
      const int tn = (t + 1 < TT) ? t + 1 : TT - 1;  // prefetch next step
      if (HAS_XG) xg_n = xg[(base + tn) * (G4 / 4) + j];
      else        xv_n = x[(base + tn) * HH + j];
    }

    // Broadcast h (lanes 0-31 hold h_j) into SGPRs.
    float hk[HH];
#pragma unroll
    for (int k = 0; k < HH; ++k)
      hk[k] = __uint_as_float(
          __builtin_amdgcn_readlane(__float_as_uint(h), k));

    float a0, a1;
    if (HAS_XG) {
      a0 = hf ? xgc.z : xgc.x;  // xg components: [i,f,g,o]
      a1 = hf ? xgc.w : xgc.y;
    } else {
      a0 = bias0;
      a1 = bias1;
    }

    if (!HAS_XG) {
      float xk[HH];
#pragma unroll
      for (int k = 0; k < HH; ++k)
        xk[k] = __uint_as_float(
            __builtin_amdgcn_readlane(__float_as_uint(xvc), k));
#pragma unroll
      for (int k = 0; k < HH; ++k) {
        a0 = fmaf(wih0[k], xk[k], a0);
        a1 = fmaf(wih1[k], xk[k], a1);
      }
    }

#pragma unroll
    for (int k = 0; k < HH; ++k) {
      a0 = fmaf(whh0[k], hk[k], a0);
      a1 = fmaf(whh1[k], hk[k], a1);
    }

    // Exchange complete pre-activations between halves.
    const float o0 = __shfl_xor(a0, 32);
    const float o1 = __shfl_xor(a1, 32);
    const float ai = hf ? o0 : a0;
    const float af = hf ? o1 : a1;
    const float ag = hf ? a0 : o0;
    const float ao = hf ? a1 : o1;

    const float gi = fsig(ai);
    const float gf = fsig(af);
    const float gg = ftanh(ag);
    const float go = fsig(ao);
    c = fmaf(gf, c, gi * gg);
    h = go * ftanh(c);

    if (!hf)
      out[(base + t) * HH + j] = fminf(fmaxf(h, -1.f), 1.f);
  }
}

extern "C" void kernel_launch(void* const* d_in, const int* in_sizes, int n_in,
                              void* d_out, int out_size, void* d_ws,
                              size_t ws_size, hipStream_t stream) {
  const float* x    = (const float*)d_in[0];
  const float* W_ih = (const float*)d_in[1];
  const float* W_hh = (const float*)d_in[2];
  const float* b_ih = (const float*)d_in[3];
  const float* b_hh = (const float*)d_in[4];
  float* out = (float*)d_out;

  const size_t need = (size_t)BB * TT * G4 * sizeof(float);  // 256 MiB
  if (ws_size >= need) {
    float* xg = (float*)d_ws;
    xproj_kernel<<<BB * TT / POS, 128, 0, stream>>>(x, W_ih, b_ih, b_hh, xg);
    lstm_rec<true><<<BB, 64, 0, stream>>>(x, W_ih, W_hh, b_ih, b_hh,
                                          (const float4*)xg, out);
  } else {
    lstm_rec<false><<<BB, 64, 0, stream>>>(x, W_ih, W_hh, b_ih, b_hh, nullptr,
                                           out);
  }
}